// Round 13
// baseline (12888.663 us; speedup 1.0000x reference)
//
#include <hip/hip_runtime.h>
#include <math.h>
#include <float.h>

#define KE 8192        // number of edges
#define NPF 3072       // floats per edge (1024 * 3)
#define NT 1024        // threads in chain kernel (16 waves, 4 per SIMD)
#define EPT 8          // edges per thread (KE / NT)
#define NP  4          // packed pairs per thread (EPT / 2)
#define NW  16         // waves
#define TOPK_N 10

typedef unsigned long long u64;
typedef float v2f __attribute__((ext_vector_type(2)));

// scalar element of a packed array (k must be a compile-time constant in use)
#define GETP(arr, k) (((k) & 1) ? arr[(k) >> 1].y : arr[(k) >> 1].x)

// one DPP-min stage: x = min(x, dpp_perm(x)); masked/invalid lanes see identity
#define DPPMIN(x, ctrl, rmask)                                              \
  do {                                                                      \
    unsigned _t = (unsigned)__builtin_amdgcn_update_dpp(                    \
        (int)0xFFFFFFFF, (int)(x), (ctrl), (rmask), 0xf, false);            \
    (x) = ((x) < _t) ? (x) : _t;                                            \
  } while (0)

// IEEE squared distance, no fma contraction: matches numpy (dx*dx + dy*dy) + dz*dz
// (used for all DISCRETE decisions that must match the reference bit-for-bit)
__device__ __forceinline__ float dist2(float ax, float ay, float az,
                                       float bx, float by, float bz) {
#pragma clang fp contract(off)
  float dx = ax - bx, dy = ay - by, dz = az - bz;
  float s = (dx * dx + dy * dy) + dz * dz;
  return s;
}

// packed 2-edge squared distance, FMA form: fma(dx,dx, fma(dy,dy, dz*dz)).
// ~1ulp-relative different from numpy rounding; argmin gaps are ~1e3 ulps,
// so winner selection is unchanged (certified by the deterministic bench).
__device__ __forceinline__ v2f dist2p(v2f cx, v2f cy, v2f cz,
                                      v2f px, v2f py, v2f pz) {
  v2f dx = px - cx, dy = py - cy, dz = pz - cz;
  return __builtin_elementwise_fma(dx, dx,
           __builtin_elementwise_fma(dy, dy, dz * dz));
}

__device__ __forceinline__ float dist3(float ax, float ay, float az,
                                       float bx, float by, float bz) {
  return sqrtf(dist2(ax, ay, az, bx, by, bz));
}

extern "C" __global__ void __launch_bounds__(NT, 1)
chain_kernel(const float* __restrict__ edges, float* __restrict__ tail,
             int* __restrict__ ws_order, int* __restrict__ ws_flip,
             float* __restrict__ tbl)
{
  const int tid = threadIdx.x;
  const int lane = tid & 63;
  const int wid = tid >> 6;          // 0..15
  const int base = tid * EPT;

  __shared__ __align__(16) u64 kbuf[2][NW];  // per-wave best (d2bits<<32|idx)
  __shared__ float  s_v[NW];
  __shared__ int    s_i[NW];
  __shared__ float  s_m1[NW], s_m2[NW];
  __shared__ unsigned pk_lds[KE];    // (widx<<1)|flip per step
  __shared__ unsigned d2_lds[KE];    // d^2 bits per step (sqrt at flush)

  // ---- load endpoints of my 8 edges into packed float2 registers ----
  v2f sxp[NP], syp[NP], szp[NP], exp_[NP], eyp[NP], ezp[NP];
#pragma unroll
  for (int e = 0; e < EPT; ++e) {
    const float* p = edges + (size_t)(base + e) * NPF;
    float a0 = p[0], a1 = p[1], a2 = p[2];
    float b0 = p[NPF - 3], b1 = p[NPF - 2], b2 = p[NPF - 1];
    if (e & 1) {
      sxp[e >> 1].y = a0; syp[e >> 1].y = a1; szp[e >> 1].y = a2;
      exp_[e >> 1].y = b0; eyp[e >> 1].y = b1; ezp[e >> 1].y = b2;
    } else {
      sxp[e >> 1].x = a0; syp[e >> 1].x = a1; szp[e >> 1].x = a2;
      exp_[e >> 1].x = b0; eyp[e >> 1].x = b1; ezp[e >> 1].x = b2;
    }
  }

  // ---- write compact endpoint table (32B/edge, L2-resident) ----
  if (tbl) {
#pragma unroll
    for (int e = 0; e < EPT; ++e) {
      float4 a, b;
      a.x = GETP(sxp, e); a.y = GETP(syp, e); a.z = GETP(szp, e); a.w = GETP(exp_, e);
      b.x = GETP(eyp, e); b.y = GETP(ezp, e); b.z = 0.f; b.w = 0.f;
      ((float4*)tbl)[(size_t)(base + e) * 2]     = a;
      ((float4*)tbl)[(size_t)(base + e) * 2 + 1] = b;
    }
  }

  // ---- lengths; top-10 longest; start_index = max index among them ----
  // (reference's score is exactly 0 at each candidate minus 1e-9*idx, so
  //  argmin(score) picks the LARGEST candidate index among the top-10)
  float len[EPT];
#pragma unroll
  for (int e = 0; e < EPT; ++e)
    len[e] = dist3(GETP(exp_, e), GETP(eyp, e), GETP(ezp, e),
                   GETP(sxp, e), GETP(syp, e), GETP(szp, e));

  unsigned tk = 0;          // bits of my edges already taken into top-k
  int start_index = -1;
  for (int r = 0; r < TOPK_N; ++r) {
    float bv = -INFINITY; int bi = 0x7fffffff;
#pragma unroll
    for (int e = 0; e < EPT; ++e) {
      if ((tk >> e) & 1) continue;
      if (len[e] > bv) { bv = len[e]; bi = base + e; }
    }
    for (int m = 1; m < 64; m <<= 1) {
      float v2 = __shfl_xor(bv, m); int i2 = __shfl_xor(bi, m);
      if (v2 > bv || (v2 == bv && i2 < bi)) { bv = v2; bi = i2; }
    }
    if (lane == 0) { s_v[wid] = bv; s_i[wid] = bi; }
    __syncthreads();
    {
      float cv = s_v[lane & (NW - 1)]; int ci = s_i[lane & (NW - 1)];
      for (int m = 1; m < NW; m <<= 1) {
        float v2 = __shfl_xor(cv, m); int i2 = __shfl_xor(ci, m);
        if (v2 > cv || (v2 == cv && i2 < ci)) { cv = v2; ci = i2; }
      }
      int sel = ci;                      // uniform across all threads
      if ((sel / EPT) == tid) tk |= 1u << (sel & (EPT - 1));
      if (sel > start_index) start_index = sel;
    }
    __syncthreads();                     // protect s_v/s_i rewrite next round
  }

  // ---- s0 / e0: uniform global load ----
  float s0x, s0y, s0z, e0x, e0y, e0z;
  {
    const float* p = edges + (size_t)start_index * NPF;
    s0x = p[0];       s0y = p[1];       s0z = p[2];
    e0x = p[NPF - 3]; e0y = p[NPF - 2]; e0z = p[NPF - 1];
  }

  // ---- use_flip0: min dist from s0 vs e0 to all OTHER edges' endpoints ----
  // numpy-exact squared mins; sqrt(min) == min(sqrt) exactly (monotone).
  {
    float m1 = INFINITY, m2 = INFINITY;
#pragma unroll
    for (int e = 0; e < EPT; ++e) {
      int k = base + e;
      float a = dist2(s0x, s0y, s0z, GETP(sxp, e), GETP(syp, e), GETP(szp, e));
      float b = dist2(s0x, s0y, s0z, GETP(exp_, e), GETP(eyp, e), GETP(ezp, e));
      float c = dist2(e0x, e0y, e0z, GETP(sxp, e), GETP(syp, e), GETP(szp, e));
      float d = dist2(e0x, e0y, e0z, GETP(exp_, e), GETP(eyp, e), GETP(ezp, e));
      float v1 = fminf(a, b), v2 = fminf(c, d);
      if (k == start_index) { v1 = INFINITY; v2 = INFINITY; }
      m1 = fminf(m1, v1);
      m2 = fminf(m2, v2);
    }
    for (int m = 1; m < 64; m <<= 1) {
      m1 = fminf(m1, __shfl_xor(m1, m));
      m2 = fminf(m2, __shfl_xor(m2, m));
    }
    if (lane == 0) { s_m1[wid] = m1; s_m2[wid] = m2; }
  }
  __syncthreads();

  float cx, cy, cz;        // current chain end
  float fx, fy, fz;        // first point of the chain (for closing distance)
  {
    float m1 = s_m1[lane & (NW - 1)], m2 = s_m2[lane & (NW - 1)];
    for (int m = 1; m < NW; m <<= 1) {
      m1 = fminf(m1, __shfl_xor(m1, m));
      m2 = fminf(m2, __shfl_xor(m2, m));
    }
    int flip0 = (sqrtf(m1) < sqrtf(m2)) ? 1 : 0;   // uniform on all threads
    cx = flip0 ? s0x : e0x;  cy = flip0 ? s0y : e0y;  cz = flip0 ? s0z : e0z;
    fx = flip0 ? e0x : s0x;  fy = flip0 ? e0y : s0y;  fz = flip0 ? e0z : s0z;
    if (tid == 0)
      pk_lds[0] = ((unsigned)start_index << 1) | (unsigned)flip0;
  }

  // consume the start edge: poison its x-coords -> d^2 = +inf forever
  if (tid == (start_index / EPT)) {
    int e = start_index & (EPT - 1);
#pragma unroll
    for (int k = 0; k < NP; ++k) {
      if ((e >> 1) == k) {
        if (e & 1) { sxp[k].y = INFINITY; exp_[k].y = INFINITY; }
        else       { sxp[k].x = INFINITY; exp_[k].x = INFINITY; }
      }
    }
  }

  // ---- greedy chain: 8191 steps, ONE barrier per step, NO global stores ----
  for (int t = 0; t < KE - 1; ++t) {
    const int pb = t & 1;

    // (A) packed FMA scan of my 8 edges vs cur: 4 (v,idx) accumulators
    v2f cx2 = {cx, cx}, cy2 = {cy, cy}, cz2 = {cz, cz};
    float av0 = INFINITY, av1 = INFINITY, av2 = INFINITY, av3 = INFINITY;
    int   ai0 = 0, ai1 = 0, ai2 = 0, ai3 = 0;
#pragma unroll
    for (int p = 0; p < NP; p += 2) {
      {
        v2f d2s = dist2p(cx2, cy2, cz2, sxp[p], syp[p], szp[p]);
        v2f d2e = dist2p(cx2, cy2, cz2, exp_[p], eyp[p], ezp[p]);
        v2f dm = __builtin_elementwise_min(d2s, d2e);
        if (dm.x < av0) { av0 = dm.x; ai0 = base + 2 * p; }
        if (dm.y < av2) { av2 = dm.y; ai2 = base + 2 * p + 1; }
      }
      {
        v2f d2s = dist2p(cx2, cy2, cz2, sxp[p+1], syp[p+1], szp[p+1]);
        v2f d2e = dist2p(cx2, cy2, cz2, exp_[p+1], eyp[p+1], ezp[p+1]);
        v2f dm = __builtin_elementwise_min(d2s, d2e);
        if (dm.x < av1) { av1 = dm.x; ai1 = base + 2 * p + 2; }
        if (dm.y < av3) { av3 = dm.y; ai3 = base + 2 * p + 3; }
      }
    }
    // lexicographic merge (value, then lowest index)
    float mv = av0; int mi = ai0;
    if (av1 < mv || (av1 == mv && ai1 < mi)) { mv = av1; mi = ai1; }
    if (av2 < mv || (av2 == mv && ai2 < mi)) { mv = av2; mi = ai2; }
    if (av3 < mv || (av3 == mv && ai3 < mi)) { mv = av3; mi = ai3; }

    // (B) DPP wave min (uint order == float order for d2 >= 0)
    unsigned mvb = __float_as_uint(mv);
    unsigned x = mvb;
    DPPMIN(x, 0x111, 0xf);   // row_shr:1
    DPPMIN(x, 0x112, 0xf);   // row_shr:2
    DPPMIN(x, 0x114, 0xf);   // row_shr:4
    DPPMIN(x, 0x118, 0xf);   // row_shr:8
    DPPMIN(x, 0x142, 0xa);   // row_bcast15 -> rows 1,3
    DPPMIN(x, 0x143, 0xc);   // row_bcast31 -> rows 2,3
    unsigned wmin = (unsigned)__builtin_amdgcn_readlane((int)x, 63);

    u64 ball = __ballot(mvb == wmin);
    int win_lane = __ffsll(ball) - 1;    // lowest lane = lowest index block
    if (lane == win_lane)
      kbuf[pb][wid] = ((u64)wmin << 32) | (unsigned)mi;
    __syncthreads();

    // (C) all threads: 16-entry min tree via f64 min (bit order == u64 order
    // for positive payloads; exponent field <= 0x7F8 so never NaN/inf)
    const double2* kp = (const double2*)&kbuf[pb][0];
    double2 q0 = kp[0], q1 = kp[1], q2 = kp[2], q3 = kp[3];
    double2 q4 = kp[4], q5 = kp[5], q6 = kp[6], q7 = kp[7];
    double m01 = fmin(fmin(q0.x, q0.y), fmin(q1.x, q1.y));
    double m23 = fmin(fmin(q2.x, q2.y), fmin(q3.x, q3.y));
    double m45 = fmin(fmin(q4.x, q4.y), fmin(q5.x, q5.y));
    double m67 = fmin(fmin(q6.x, q6.y), fmin(q7.x, q7.y));
    u64 kb = (u64)__double_as_longlong(fmin(fmin(m01, m23), fmin(m45, m67)));
    int widx = __builtin_amdgcn_readfirstlane((int)(kb & 0xFFFFFFFFu));

    // winner coords: compact table (L2-hot) or edges fallback
    float osx, osy, osz, oex, oey, oez;
    if (tbl) {
      const float4* wp = (const float4*)tbl + (size_t)widx * 2;
      float4 a = wp[0], b = wp[1];
      osx = a.x; osy = a.y; osz = a.z; oex = a.w; oey = b.x; oez = b.y;
    } else {
      const float* wp = edges + (size_t)widx * NPF;
      osx = wp[0]; osy = wp[1]; osz = wp[2];
      oex = wp[NPF - 3]; oey = wp[NPF - 2]; oez = wp[NPF - 1];
    }

    // flip: numpy-exact semantics (exact dist2 + exact sqrt compare)
    float da2 = dist2(cx, cy, cz, osx, osy, osz);
    float db2 = dist2(cx, cy, cz, oex, oey, oez);
    int fl = (sqrtf(da2) > sqrtf(db2)) ? 1 : 0;
    cx = fl ? osx : oex;
    cy = fl ? osy : oey;
    cz = fl ? osz : oez;

    if (tid == (widx >> 3)) {               // owner bookkeeping (LDS only)
      int e = widx & (EPT - 1);
#pragma unroll
      for (int k = 0; k < NP; ++k) {
        if ((e >> 1) == k) {
          if (e & 1) { sxp[k].y = INFINITY; exp_[k].y = INFINITY; }
          else       { sxp[k].x = INFINITY; exp_[k].x = INFINITY; }
        }
      }
      pk_lds[t + 1] = ((unsigned)widx << 1) | (unsigned)fl;
      d2_lds[t]     = (unsigned)(kb >> 32);
    }
  }

  // closing squared distance -> d2_lds[KE-1] (sqrt at flush)
  if (tid == 0)
    d2_lds[KE - 1] = __float_as_uint(dist2(cx, cy, cz, fx, fy, fz));
  __syncthreads();

  // ---- final flush: LDS -> global (order | flips | distances | ws) ----
  float* ord_f = tail;
  float* flp_f = tail + KE;
  float* dst_f = tail + 2 * KE;
#pragma unroll
  for (int k = 0; k < EPT; ++k) {
    int i = tid + k * NT;
    unsigned p = pk_lds[i];
    int w = (int)(p >> 1);
    int f = (int)(p & 1u);
    ord_f[i] = (float)w;
    flp_f[i] = (float)f;
    dst_f[i] = sqrtf(__uint_as_float(d2_lds[i]));
    ws_order[i] = w;
    ws_flip[i]  = f;
  }
}

extern "C" __global__ void __launch_bounds__(256)
gather_kernel(const float* __restrict__ edges, const int* __restrict__ ws_order,
              const int* __restrict__ ws_flip, float* __restrict__ out)
{
  int idx = blockIdx.x * 256 + threadIdx.x;   // < 25165824, fits int
  int i = idx / NPF;
  int f = idx - i * NPF;
  int o  = ws_order[i];
  int fl = ws_flip[i];
  int r = f / 3;
  int c = f - r * 3;
  int srcf = fl ? ((1023 - r) * 3 + c) : f;
  out[idx] = edges[o * NPF + srcf];
}

extern "C" void kernel_launch(void* const* d_in, const int* in_sizes, int n_in,
                              void* d_out, int out_size, void* d_ws, size_t ws_size,
                              hipStream_t stream) {
  (void)in_sizes; (void)n_in; (void)out_size;
  const float* edges = (const float*)d_in[0];
  float* out  = (float*)d_out;
  float* tail = out + (size_t)KE * NPF;        // order | flips | distances
  int* ws_order = (int*)d_ws;
  int* ws_flip  = ws_order + KE;
  size_t need = (size_t)2 * KE * sizeof(int) + (size_t)KE * 8 * sizeof(float);
  float* tbl = (ws_size >= need) ? (float*)((char*)d_ws + (size_t)2 * KE * sizeof(int))
                                 : nullptr;

  hipLaunchKernelGGL(chain_kernel, dim3(1), dim3(NT), 0, stream,
                     edges, tail, ws_order, ws_flip, tbl);
  hipLaunchKernelGGL(gather_kernel, dim3((KE * NPF) / 256), dim3(256), 0, stream,
                     edges, ws_order, ws_flip, out);
}

// Round 14
// 10884.675 us; speedup vs baseline: 1.1841x; 1.1841x over previous
//
#include <hip/hip_runtime.h>
#include <math.h>
#include <float.h>

#define KE 8192        // number of edges
#define NPF 3072       // floats per edge (1024 * 3)
#define NT 512         // threads in chain kernel (8 waves, 2 per SIMD)
#define EPT 16         // edges per thread in phase 0
#define NW  8          // waves
#define TOPK_N 10

typedef unsigned long long u64;
typedef float v2f __attribute__((ext_vector_type(2)));

#define GETP(arr, k) (((k) & 1) ? arr[(k) >> 1].y : arr[(k) >> 1].x)

#define DPPMIN(x, ctrl, rmask)                                              \
  do {                                                                      \
    unsigned _t = (unsigned)__builtin_amdgcn_update_dpp(                    \
        (int)0xFFFFFFFF, (int)(x), (ctrl), (rmask), 0xf, false);            \
    (x) = ((x) < _t) ? (x) : _t;                                            \
  } while (0)

// numpy-exact squared distance (no contraction) for DISCRETE decisions
__device__ __forceinline__ float dist2(float ax, float ay, float az,
                                       float bx, float by, float bz) {
#pragma clang fp contract(off)
  float dx = ax - bx, dy = ay - by, dz = az - bz;
  float s = (dx * dx + dy * dy) + dz * dz;
  return s;
}

// packed 2-edge squared distance, FMA form (argmin-safe; certified by bench)
__device__ __forceinline__ v2f dist2p(v2f cx, v2f cy, v2f cz,
                                      v2f px, v2f py, v2f pz) {
  v2f dx = px - cx, dy = py - cy, dz = pz - cz;
  return __builtin_elementwise_fma(dx, dx,
           __builtin_elementwise_fma(dy, dy, dz * dz));
}

__device__ __forceinline__ float dist3(float ax, float ay, float az,
                                       float bx, float by, float bz) {
  return sqrtf(dist2(ax, ay, az, bx, by, bz));
}

__device__ __forceinline__ u64 umin64(u64 a, u64 b) { return a < b ? a : b; }

// One chain phase over steps [t0,t1). EPTT edges/thread live in registers.
// FIRST: identity layout (idx = tid*EPTT + e), loads from edges, poisons the
// start edge. Otherwise: loads compacted {coords,idx} entries from cmp.
// At phase end (unless final), writes live edges back to cmp in index order.
template<int EPTT, bool FIRST>
__device__ void chain_phase(int t0, int t1,
    const float* __restrict__ edges, const float4* __restrict__ tbl4,
    float4* __restrict__ cmp, int start_index,
    float& cxr, float& cyr, float& czr,
    unsigned* pk_lds, unsigned* d2_lds,
    u64 (*kbuf)[NW], int* s_int, int tid)
{
  constexpr int NPT = EPTT / 2;
  const int lane = tid & 63;
  const int wid  = tid >> 6;
  const int base = tid * EPTT;

  v2f sxp[NPT], syp[NPT], szp[NPT], exp_[NPT], eyp[NPT], ezp[NPT];
  int idxs[EPTT];   // unused when FIRST (optimized out)

#pragma unroll
  for (int e = 0; e < EPTT; ++e) {
    float a0, a1, a2, b0, b1, b2;
    if constexpr (FIRST) {
      const float* p = edges + (size_t)(base + e) * NPF;
      a0 = p[0]; a1 = p[1]; a2 = p[2];
      b0 = p[NPF - 3]; b1 = p[NPF - 2]; b2 = p[NPF - 1];
    } else {
      float4 a = cmp[(size_t)(base + e) * 2];
      float4 b = cmp[(size_t)(base + e) * 2 + 1];
      a0 = a.x; a1 = a.y; a2 = a.z; b0 = a.w; b1 = b.x; b2 = b.y;
      idxs[e] = __float_as_int(b.z);
    }
    if (e & 1) {
      sxp[e >> 1].y = a0; syp[e >> 1].y = a1; szp[e >> 1].y = a2;
      exp_[e >> 1].y = b0; eyp[e >> 1].y = b1; ezp[e >> 1].y = b2;
    } else {
      sxp[e >> 1].x = a0; syp[e >> 1].x = a1; szp[e >> 1].x = a2;
      exp_[e >> 1].x = b0; eyp[e >> 1].x = b1; ezp[e >> 1].x = b2;
    }
  }
  unsigned alive = (unsigned)((1u << EPTT) - 1);

  if constexpr (FIRST) {
    // consume the start edge: poison x-coords -> d^2 = +inf forever
    if (tid == (start_index / EPTT)) {
      int e = start_index & (EPTT - 1);
#pragma unroll
      for (int k = 0; k < NPT; ++k) {
        if ((e >> 1) == k) {
          if (e & 1) { sxp[k].y = INFINITY; exp_[k].y = INFINITY; }
          else       { sxp[k].x = INFINITY; exp_[k].x = INFINITY; }
        }
      }
      alive &= ~(1u << e);
    }
  }

  float cx = cxr, cy = cyr, cz = czr;

  for (int t = t0; t < t1; ++t) {
    const int pb = t & 1;

    // (A) packed FMA scan: 4 (v,idx) accumulators, residue classes mod 4
    v2f cx2 = {cx, cx}, cy2 = {cy, cy}, cz2 = {cz, cz};
    float av0 = INFINITY, av1 = INFINITY, av2 = INFINITY, av3 = INFINITY;
    int   ai0 = 0x7FFFFFFF, ai1 = 0x7FFFFFFF, ai2 = 0x7FFFFFFF, ai3 = 0x7FFFFFFF;
#pragma unroll
    for (int p = 0; p < NPT; ++p) {
      v2f d2s = dist2p(cx2, cy2, cz2, sxp[p], syp[p], szp[p]);
      v2f d2e = dist2p(cx2, cy2, cz2, exp_[p], eyp[p], ezp[p]);
      v2f dm = __builtin_elementwise_min(d2s, d2e);
      int ix = FIRST ? (base + 2 * p)     : idxs[2 * p];
      int iy = FIRST ? (base + 2 * p + 1) : idxs[2 * p + 1];
      if ((p & 1) == 0) {
        if (dm.x < av0) { av0 = dm.x; ai0 = ix; }
        if (dm.y < av2) { av2 = dm.y; ai2 = iy; }
      } else {
        if (dm.x < av1) { av1 = dm.x; ai1 = ix; }
        if (dm.y < av3) { av3 = dm.y; ai3 = iy; }
      }
    }
    // lexicographic merge (value, then lowest original index)
    float mv = av0; int mi = ai0;
    if (av1 < mv || (av1 == mv && ai1 < mi)) { mv = av1; mi = ai1; }
    if (av2 < mv || (av2 == mv && ai2 < mi)) { mv = av2; mi = ai2; }
    if (av3 < mv || (av3 == mv && ai3 < mi)) { mv = av3; mi = ai3; }

    // (B) DPP wave min (uint order == float order for d2 >= 0)
    unsigned mvb = __float_as_uint(mv);
    unsigned x = mvb;
    DPPMIN(x, 0x111, 0xf);   // row_shr:1
    DPPMIN(x, 0x112, 0xf);   // row_shr:2
    DPPMIN(x, 0x114, 0xf);   // row_shr:4
    DPPMIN(x, 0x118, 0xf);   // row_shr:8
    DPPMIN(x, 0x142, 0xa);   // row_bcast15 -> rows 1,3
    DPPMIN(x, 0x143, 0xc);   // row_bcast31 -> rows 2,3
    unsigned wmin = (unsigned)__builtin_amdgcn_readlane((int)x, 63);

    u64 ball = __ballot(mvb == wmin);
    int win_lane = __ffsll(ball) - 1;    // lowest lane = lowest index block
    if (lane == win_lane)
      kbuf[pb][wid] = ((u64)wmin << 32) | (unsigned)mi;
    __syncthreads();

    // (C) 8-entry u64 min tree from LDS (broadcast reads)
    const ulonglong2* kp = (const ulonglong2*)&kbuf[pb][0];
    ulonglong2 q0 = kp[0], q1 = kp[1], q2 = kp[2], q3 = kp[3];
    u64 kb = umin64(umin64(umin64(q0.x, q0.y), umin64(q1.x, q1.y)),
                    umin64(umin64(q2.x, q2.y), umin64(q3.x, q3.y)));
    int widx = __builtin_amdgcn_readfirstlane((int)(kb & 0xFFFFFFFFu));

    // winner coords: compact table (L2-hot) or edges fallback
    float osx, osy, osz, oex, oey, oez;
    if (tbl4) {
      const float4* wp = tbl4 + (size_t)widx * 2;
      float4 a = wp[0], b = wp[1];
      osx = a.x; osy = a.y; osz = a.z; oex = a.w; oey = b.x; oez = b.y;
    } else {
      const float* wp = edges + (size_t)widx * NPF;
      osx = wp[0]; osy = wp[1]; osz = wp[2];
      oex = wp[NPF - 3]; oey = wp[NPF - 2]; oez = wp[NPF - 1];
    }

    // flip: numpy-exact (exact dist2 + exact sqrt compare)
    float da2 = dist2(cx, cy, cz, osx, osy, osz);
    float db2 = dist2(cx, cy, cz, oex, oey, oez);
    int fl = (sqrtf(da2) > sqrtf(db2)) ? 1 : 0;
    cx = fl ? osx : oex;
    cy = fl ? osy : oey;
    cz = fl ? osz : oez;

    // owner bookkeeping (LDS only)
    if constexpr (FIRST) {
      if (tid == (widx / EPTT)) {
        int e = widx & (EPTT - 1);
#pragma unroll
        for (int k = 0; k < NPT; ++k) {
          if ((e >> 1) == k) {
            if (e & 1) { sxp[k].y = INFINITY; exp_[k].y = INFINITY; }
            else       { sxp[k].x = INFINITY; exp_[k].x = INFINITY; }
          }
        }
        alive &= ~(1u << e);
        pk_lds[t + 1] = ((unsigned)widx << 1) | (unsigned)fl;
        d2_lds[t]     = (unsigned)(kb >> 32);
      }
    } else {
#pragma unroll
      for (int e = 0; e < EPTT; ++e) {
        if (idxs[e] == widx) {
          if (e & 1) { sxp[e >> 1].y = INFINITY; exp_[e >> 1].y = INFINITY; }
          else       { sxp[e >> 1].x = INFINITY; exp_[e >> 1].x = INFINITY; }
          alive &= ~(1u << e);
          pk_lds[t + 1] = ((unsigned)widx << 1) | (unsigned)fl;
          d2_lds[t]     = (unsigned)(kb >> 32);
        }
      }
    }
  }

  cxr = cx; cyr = cy; czr = cz;

  // ---- compaction write-out (skipped on the final phase) ----
  if (t1 < KE - 1) {
    int cnt = __popc(alive);
    int sc = cnt;                          // wave inclusive scan
#pragma unroll
    for (int m = 1; m < 64; m <<= 1) {
      int o = __shfl_up(sc, m);
      if (lane >= m) sc += o;
    }
    if (lane == 63) s_int[wid] = sc;
    __syncthreads();
    int wbase = 0;
#pragma unroll
    for (int w = 0; w < NW; ++w)
      if (w < wid) wbase += s_int[w];
    int pos = wbase + sc - cnt;            // exclusive global offset
#pragma unroll
    for (int e = 0; e < EPTT; ++e) {
      if ((alive >> e) & 1) {
        float4 a, b;
        a.x = GETP(sxp, e); a.y = GETP(syp, e); a.z = GETP(szp, e);
        a.w = GETP(exp_, e);
        b.x = GETP(eyp, e); b.y = GETP(ezp, e);
        b.z = __int_as_float(FIRST ? (base + e) : idxs[e]); b.w = 0.f;
        cmp[(size_t)pos * 2]     = a;
        cmp[(size_t)pos * 2 + 1] = b;
        ++pos;
      }
    }
    __threadfence();
    __syncthreads();
  }
}

extern "C" __global__ void __launch_bounds__(NT, 1)
chain_kernel(const float* __restrict__ edges, float* __restrict__ tail,
             int* __restrict__ ws_order, int* __restrict__ ws_flip,
             float* __restrict__ tbl, float4* __restrict__ cmp)
{
  const int tid = threadIdx.x;
  const int lane = tid & 63;
  const int wid = tid >> 6;          // 0..7
  const int base = tid * EPT;

  __shared__ __align__(16) u64 kbuf[2][NW];  // per-wave best (d2bits<<32|idx)
  __shared__ float  s_v[NW];
  __shared__ int    s_i[NW];
  __shared__ float  s_m1[NW], s_m2[NW];
  __shared__ unsigned pk_lds[KE];    // (widx<<1)|flip per step
  __shared__ unsigned d2_lds[KE];    // d^2 bits per step (sqrt at flush)

  // ---- init: load endpoints (local arrays, die after init) ----
  v2f sxp[EPT / 2], syp[EPT / 2], szp[EPT / 2];
  v2f exp_[EPT / 2], eyp[EPT / 2], ezp[EPT / 2];
#pragma unroll
  for (int e = 0; e < EPT; ++e) {
    const float* p = edges + (size_t)(base + e) * NPF;
    float a0 = p[0], a1 = p[1], a2 = p[2];
    float b0 = p[NPF - 3], b1 = p[NPF - 2], b2 = p[NPF - 1];
    if (e & 1) {
      sxp[e >> 1].y = a0; syp[e >> 1].y = a1; szp[e >> 1].y = a2;
      exp_[e >> 1].y = b0; eyp[e >> 1].y = b1; ezp[e >> 1].y = b2;
    } else {
      sxp[e >> 1].x = a0; syp[e >> 1].x = a1; szp[e >> 1].x = a2;
      exp_[e >> 1].x = b0; eyp[e >> 1].x = b1; ezp[e >> 1].x = b2;
    }
  }

  // ---- write compact endpoint table (32B/edge, L2-resident) ----
  if (tbl) {
#pragma unroll
    for (int e = 0; e < EPT; ++e) {
      float4 a, b;
      a.x = GETP(sxp, e); a.y = GETP(syp, e); a.z = GETP(szp, e); a.w = GETP(exp_, e);
      b.x = GETP(eyp, e); b.y = GETP(ezp, e); b.z = 0.f; b.w = 0.f;
      ((float4*)tbl)[(size_t)(base + e) * 2]     = a;
      ((float4*)tbl)[(size_t)(base + e) * 2 + 1] = b;
    }
  }

  // ---- lengths; top-10; start_index = max index among them ----
  float len[EPT];
#pragma unroll
  for (int e = 0; e < EPT; ++e)
    len[e] = dist3(GETP(exp_, e), GETP(eyp, e), GETP(ezp, e),
                   GETP(sxp, e), GETP(syp, e), GETP(szp, e));

  unsigned tk = 0;
  int start_index = -1;
  for (int r = 0; r < TOPK_N; ++r) {
    float bv = -INFINITY; int bi = 0x7fffffff;
#pragma unroll
    for (int e = 0; e < EPT; ++e) {
      if ((tk >> e) & 1) continue;
      if (len[e] > bv) { bv = len[e]; bi = base + e; }
    }
    for (int m = 1; m < 64; m <<= 1) {
      float v2 = __shfl_xor(bv, m); int i2 = __shfl_xor(bi, m);
      if (v2 > bv || (v2 == bv && i2 < bi)) { bv = v2; bi = i2; }
    }
    if (lane == 0) { s_v[wid] = bv; s_i[wid] = bi; }
    __syncthreads();
    {
      float cv = s_v[lane & (NW - 1)]; int ci = s_i[lane & (NW - 1)];
      for (int m = 1; m < NW; m <<= 1) {
        float v2 = __shfl_xor(cv, m); int i2 = __shfl_xor(ci, m);
        if (v2 > cv || (v2 == cv && i2 < ci)) { cv = v2; ci = i2; }
      }
      int sel = ci;
      if ((sel / EPT) == tid) tk |= 1u << (sel & (EPT - 1));
      if (sel > start_index) start_index = sel;
    }
    __syncthreads();
  }

  // ---- s0 / e0: uniform global load ----
  float s0x, s0y, s0z, e0x, e0y, e0z;
  {
    const float* p = edges + (size_t)start_index * NPF;
    s0x = p[0];       s0y = p[1];       s0z = p[2];
    e0x = p[NPF - 3]; e0y = p[NPF - 2]; e0z = p[NPF - 1];
  }

  // ---- use_flip0 (numpy-exact; sqrt(min)==min(sqrt)) ----
  {
    float m1 = INFINITY, m2 = INFINITY;
#pragma unroll
    for (int e = 0; e < EPT; ++e) {
      int k = base + e;
      float a = dist2(s0x, s0y, s0z, GETP(sxp, e), GETP(syp, e), GETP(szp, e));
      float b = dist2(s0x, s0y, s0z, GETP(exp_, e), GETP(eyp, e), GETP(ezp, e));
      float c = dist2(e0x, e0y, e0z, GETP(sxp, e), GETP(syp, e), GETP(szp, e));
      float d = dist2(e0x, e0y, e0z, GETP(exp_, e), GETP(eyp, e), GETP(ezp, e));
      float v1 = fminf(a, b), v2 = fminf(c, d);
      if (k == start_index) { v1 = INFINITY; v2 = INFINITY; }
      m1 = fminf(m1, v1);
      m2 = fminf(m2, v2);
    }
    for (int m = 1; m < 64; m <<= 1) {
      m1 = fminf(m1, __shfl_xor(m1, m));
      m2 = fminf(m2, __shfl_xor(m2, m));
    }
    if (lane == 0) { s_m1[wid] = m1; s_m2[wid] = m2; }
  }
  __syncthreads();

  float cx, cy, cz, fx, fy, fz;
  {
    float m1 = s_m1[lane & (NW - 1)], m2 = s_m2[lane & (NW - 1)];
    for (int m = 1; m < NW; m <<= 1) {
      m1 = fminf(m1, __shfl_xor(m1, m));
      m2 = fminf(m2, __shfl_xor(m2, m));
    }
    int flip0 = (sqrtf(m1) < sqrtf(m2)) ? 1 : 0;
    cx = flip0 ? s0x : e0x;  cy = flip0 ? s0y : e0y;  cz = flip0 ? s0z : e0z;
    fx = flip0 ? e0x : s0x;  fy = flip0 ? e0y : s0y;  fz = flip0 ? e0z : s0z;
    if (tid == 0)
      pk_lds[0] = ((unsigned)start_index << 1) | (unsigned)flip0;
  }
  __syncthreads();

  // ---- phased greedy chain ----
  // live(before step t) = 8191-t; boundaries where live == 512*EPT'
  if (cmp) {
    chain_phase<16, true >(0,    4095, edges, (const float4*)tbl, cmp,
                           start_index, cx, cy, cz, pk_lds, d2_lds, kbuf, s_i, tid);
    chain_phase<8, false>(4095, 6143, edges, (const float4*)tbl, cmp,
                           start_index, cx, cy, cz, pk_lds, d2_lds, kbuf, s_i, tid);
    chain_phase<4, false>(6143, 7167, edges, (const float4*)tbl, cmp,
                           start_index, cx, cy, cz, pk_lds, d2_lds, kbuf, s_i, tid);
    chain_phase<2, false>(7167, KE - 1, edges, (const float4*)tbl, cmp,
                           start_index, cx, cy, cz, pk_lds, d2_lds, kbuf, s_i, tid);
  } else {
    chain_phase<16, true >(0, KE - 1, edges, (const float4*)tbl, cmp,
                           start_index, cx, cy, cz, pk_lds, d2_lds, kbuf, s_i, tid);
  }

  // closing squared distance -> d2_lds[KE-1] (sqrt at flush)
  if (tid == 0)
    d2_lds[KE - 1] = __float_as_uint(dist2(cx, cy, cz, fx, fy, fz));
  __syncthreads();

  // ---- final flush: LDS -> global (order | flips | distances | ws) ----
  float* ord_f = tail;
  float* flp_f = tail + KE;
  float* dst_f = tail + 2 * KE;
#pragma unroll
  for (int k = 0; k < EPT; ++k) {
    int i = tid + k * NT;
    unsigned p = pk_lds[i];
    int w = (int)(p >> 1);
    int f = (int)(p & 1u);
    ord_f[i] = (float)w;
    flp_f[i] = (float)f;
    dst_f[i] = sqrtf(__uint_as_float(d2_lds[i]));
    ws_order[i] = w;
    ws_flip[i]  = f;
  }
}

extern "C" __global__ void __launch_bounds__(256)
gather_kernel(const float* __restrict__ edges, const int* __restrict__ ws_order,
              const int* __restrict__ ws_flip, float* __restrict__ out)
{
  int idx = blockIdx.x * 256 + threadIdx.x;   // < 25165824, fits int
  int i = idx / NPF;
  int f = idx - i * NPF;
  int o  = ws_order[i];
  int fl = ws_flip[i];
  int r = f / 3;
  int c = f - r * 3;
  int srcf = fl ? ((1023 - r) * 3 + c) : f;
  out[idx] = edges[o * NPF + srcf];
}

extern "C" void kernel_launch(void* const* d_in, const int* in_sizes, int n_in,
                              void* d_out, int out_size, void* d_ws, size_t ws_size,
                              hipStream_t stream) {
  (void)in_sizes; (void)n_in; (void)out_size;
  const float* edges = (const float*)d_in[0];
  float* out  = (float*)d_out;
  float* tail = out + (size_t)KE * NPF;        // order | flips | distances
  int* ws_order = (int*)d_ws;
  int* ws_flip  = ws_order + KE;
  size_t need_tbl = (size_t)2 * KE * sizeof(int) + (size_t)KE * 8 * sizeof(float);
  size_t need_cmp = need_tbl + (size_t)4096 * 8 * sizeof(float);
  float* tbl = (ws_size >= need_tbl)
                 ? (float*)((char*)d_ws + (size_t)2 * KE * sizeof(int)) : nullptr;
  float4* cmp = (ws_size >= need_cmp && tbl)
                 ? (float4*)((char*)d_ws + need_tbl) : nullptr;

  hipLaunchKernelGGL(chain_kernel, dim3(1), dim3(NT), 0, stream,
                     edges, tail, ws_order, ws_flip, tbl, cmp);
  hipLaunchKernelGGL(gather_kernel, dim3((KE * NPF) / 256), dim3(256), 0, stream,
                     edges, ws_order, ws_flip, out);
}

// Round 15
// 10778.358 us; speedup vs baseline: 1.1958x; 1.0099x over previous
//
#include <hip/hip_runtime.h>
#include <math.h>
#include <float.h>

#define KE 8192        // number of edges
#define NPF 3072       // floats per edge (1024 * 3)
#define NT 512         // threads in chain kernel (8 waves, 2 per SIMD)
#define EPT 16         // edges per thread in phase 0
#define NW  8          // waves
#define TOPK_N 10

typedef unsigned long long u64;
typedef float v2f __attribute__((ext_vector_type(2)));

#define GETP(arr, k) (((k) & 1) ? arr[(k) >> 1].y : arr[(k) >> 1].x)

#define DPPMIN(x, ctrl, rmask)                                              \
  do {                                                                      \
    unsigned _t = (unsigned)__builtin_amdgcn_update_dpp(                    \
        (int)0xFFFFFFFF, (int)(x), (ctrl), (rmask), 0xf, false);            \
    (x) = ((x) < _t) ? (x) : _t;                                            \
  } while (0)

// numpy-exact squared distance (no contraction) for DISCRETE decisions
__device__ __forceinline__ float dist2(float ax, float ay, float az,
                                       float bx, float by, float bz) {
#pragma clang fp contract(off)
  float dx = ax - bx, dy = ay - by, dz = az - bz;
  float s = (dx * dx + dy * dy) + dz * dz;
  return s;
}

// packed 2-edge squared distance, FMA form (argmin-safe; certified by bench)
__device__ __forceinline__ v2f dist2p(v2f cx, v2f cy, v2f cz,
                                      v2f px, v2f py, v2f pz) {
  v2f dx = px - cx, dy = py - cy, dz = pz - cz;
  return __builtin_elementwise_fma(dx, dx,
           __builtin_elementwise_fma(dy, dy, dz * dz));
}

__device__ __forceinline__ float dist3(float ax, float ay, float az,
                                       float bx, float by, float bz) {
  return sqrtf(dist2(ax, ay, az, bx, by, bz));
}

__device__ __forceinline__ u64 umin64(u64 a, u64 b) { return a < b ? a : b; }

// One chain phase over steps [t0,t1). EPTT edges/thread live in registers.
template<int EPTT, bool FIRST>
__device__ void chain_phase(int t0, int t1,
    const float* __restrict__ edges, const float4* __restrict__ tbl4,
    float4* __restrict__ cmp, int start_index,
    float& cxr, float& cyr, float& czr,
    unsigned* pk_lds, unsigned* d2_lds,
    u64 (*kbuf)[NW], int* s_int, int tid)
{
  constexpr int NPT = EPTT / 2;
  const int lane = tid & 63;
  const int wid  = tid >> 6;
  const int base = tid * EPTT;

  v2f sxp[NPT], syp[NPT], szp[NPT], exp_[NPT], eyp[NPT], ezp[NPT];
  int idxs[EPTT];   // unused when FIRST (optimized out)

#pragma unroll
  for (int e = 0; e < EPTT; ++e) {
    float a0, a1, a2, b0, b1, b2;
    if constexpr (FIRST) {
      const float* p = edges + (size_t)(base + e) * NPF;
      a0 = p[0]; a1 = p[1]; a2 = p[2];
      b0 = p[NPF - 3]; b1 = p[NPF - 2]; b2 = p[NPF - 1];
    } else {
      float4 a = cmp[(size_t)(base + e) * 2];
      float4 b = cmp[(size_t)(base + e) * 2 + 1];
      a0 = a.x; a1 = a.y; a2 = a.z; b0 = a.w; b1 = b.x; b2 = b.y;
      idxs[e] = __float_as_int(b.z);
    }
    if (e & 1) {
      sxp[e >> 1].y = a0; syp[e >> 1].y = a1; szp[e >> 1].y = a2;
      exp_[e >> 1].y = b0; eyp[e >> 1].y = b1; ezp[e >> 1].y = b2;
    } else {
      sxp[e >> 1].x = a0; syp[e >> 1].x = a1; szp[e >> 1].x = a2;
      exp_[e >> 1].x = b0; eyp[e >> 1].x = b1; ezp[e >> 1].x = b2;
    }
  }
  unsigned alive = (unsigned)((1u << EPTT) - 1);

  if constexpr (FIRST) {
    if (tid == (start_index / EPTT)) {
      int e = start_index & (EPTT - 1);
#pragma unroll
      for (int k = 0; k < NPT; ++k) {
        if ((e >> 1) == k) {
          if (e & 1) { sxp[k].y = INFINITY; exp_[k].y = INFINITY; }
          else       { sxp[k].x = INFINITY; exp_[k].x = INFINITY; }
        }
      }
      alive &= ~(1u << e);
    }
  }

  float cx = cxr, cy = cyr, cz = czr;

  for (int t = t0; t < t1; ++t) {
    const int pb = t & 1;

    v2f cx2 = {cx, cx}, cy2 = {cy, cy}, cz2 = {cz, cz};
    float av0 = INFINITY, av1 = INFINITY, av2 = INFINITY, av3 = INFINITY;
    int   ai0 = 0x7FFFFFFF, ai1 = 0x7FFFFFFF, ai2 = 0x7FFFFFFF, ai3 = 0x7FFFFFFF;
#pragma unroll
    for (int p = 0; p < NPT; ++p) {
      v2f d2s = dist2p(cx2, cy2, cz2, sxp[p], syp[p], szp[p]);
      v2f d2e = dist2p(cx2, cy2, cz2, exp_[p], eyp[p], ezp[p]);
      v2f dm = __builtin_elementwise_min(d2s, d2e);
      int ix = FIRST ? (base + 2 * p)     : idxs[2 * p];
      int iy = FIRST ? (base + 2 * p + 1) : idxs[2 * p + 1];
      if ((p & 1) == 0) {
        if (dm.x < av0) { av0 = dm.x; ai0 = ix; }
        if (dm.y < av2) { av2 = dm.y; ai2 = iy; }
      } else {
        if (dm.x < av1) { av1 = dm.x; ai1 = ix; }
        if (dm.y < av3) { av3 = dm.y; ai3 = iy; }
      }
    }
    float mv = av0; int mi = ai0;
    if (av1 < mv || (av1 == mv && ai1 < mi)) { mv = av1; mi = ai1; }
    if (av2 < mv || (av2 == mv && ai2 < mi)) { mv = av2; mi = ai2; }
    if (av3 < mv || (av3 == mv && ai3 < mi)) { mv = av3; mi = ai3; }

    unsigned mvb = __float_as_uint(mv);
    unsigned x = mvb;
    DPPMIN(x, 0x111, 0xf);
    DPPMIN(x, 0x112, 0xf);
    DPPMIN(x, 0x114, 0xf);
    DPPMIN(x, 0x118, 0xf);
    DPPMIN(x, 0x142, 0xa);
    DPPMIN(x, 0x143, 0xc);
    unsigned wmin = (unsigned)__builtin_amdgcn_readlane((int)x, 63);

    u64 ball = __ballot(mvb == wmin);
    int win_lane = __ffsll(ball) - 1;
    if (lane == win_lane)
      kbuf[pb][wid] = ((u64)wmin << 32) | (unsigned)mi;
    __syncthreads();

    const ulonglong2* kp = (const ulonglong2*)&kbuf[pb][0];
    ulonglong2 q0 = kp[0], q1 = kp[1], q2 = kp[2], q3 = kp[3];
    u64 kb = umin64(umin64(umin64(q0.x, q0.y), umin64(q1.x, q1.y)),
                    umin64(umin64(q2.x, q2.y), umin64(q3.x, q3.y)));
    int widx = __builtin_amdgcn_readfirstlane((int)(kb & 0xFFFFFFFFu));

    float osx, osy, osz, oex, oey, oez;
    if (tbl4) {
      const float4* wp = tbl4 + (size_t)widx * 2;
      float4 a = wp[0], b = wp[1];
      osx = a.x; osy = a.y; osz = a.z; oex = a.w; oey = b.x; oez = b.y;
    } else {
      const float* wp = edges + (size_t)widx * NPF;
      osx = wp[0]; osy = wp[1]; osz = wp[2];
      oex = wp[NPF - 3]; oey = wp[NPF - 2]; oez = wp[NPF - 1];
    }

    float da2 = dist2(cx, cy, cz, osx, osy, osz);
    float db2 = dist2(cx, cy, cz, oex, oey, oez);
    int fl = (sqrtf(da2) > sqrtf(db2)) ? 1 : 0;
    cx = fl ? osx : oex;
    cy = fl ? osy : oey;
    cz = fl ? osz : oez;

    if constexpr (FIRST) {
      if (tid == (widx / EPTT)) {
        int e = widx & (EPTT - 1);
#pragma unroll
        for (int k = 0; k < NPT; ++k) {
          if ((e >> 1) == k) {
            if (e & 1) { sxp[k].y = INFINITY; exp_[k].y = INFINITY; }
            else       { sxp[k].x = INFINITY; exp_[k].x = INFINITY; }
          }
        }
        alive &= ~(1u << e);
        pk_lds[t + 1] = ((unsigned)widx << 1) | (unsigned)fl;
        d2_lds[t]     = (unsigned)(kb >> 32);
      }
    } else {
#pragma unroll
      for (int e = 0; e < EPTT; ++e) {
        if (idxs[e] == widx) {
          if (e & 1) { sxp[e >> 1].y = INFINITY; exp_[e >> 1].y = INFINITY; }
          else       { sxp[e >> 1].x = INFINITY; exp_[e >> 1].x = INFINITY; }
          alive &= ~(1u << e);
          pk_lds[t + 1] = ((unsigned)widx << 1) | (unsigned)fl;
          d2_lds[t]     = (unsigned)(kb >> 32);
        }
      }
    }
  }

  cxr = cx; cyr = cy; czr = cz;

  // ---- compaction write-out (live edges, in ascending original index) ----
  if (t1 < KE - 1) {
    int cnt = __popc(alive);
    int sc = cnt;
#pragma unroll
    for (int m = 1; m < 64; m <<= 1) {
      int o = __shfl_up(sc, m);
      if (lane >= m) sc += o;
    }
    if (lane == 63) s_int[wid] = sc;
    __syncthreads();
    int wbase = 0;
#pragma unroll
    for (int w = 0; w < NW; ++w)
      if (w < wid) wbase += s_int[w];
    int pos = wbase + sc - cnt;
#pragma unroll
    for (int e = 0; e < EPTT; ++e) {
      if ((alive >> e) & 1) {
        float4 a, b;
        a.x = GETP(sxp, e); a.y = GETP(syp, e); a.z = GETP(szp, e);
        a.w = GETP(exp_, e);
        b.x = GETP(eyp, e); b.y = GETP(ezp, e);
        b.z = __int_as_float(FIRST ? (base + e) : idxs[e]); b.w = 0.f;
        cmp[(size_t)pos * 2]     = a;
        cmp[(size_t)pos * 2 + 1] = b;
        ++pos;
      }
    }
    __threadfence();
    __syncthreads();
  }
}

// Single-wave tail: live <= 1024, wave 0 only, NO barriers, NO cross-wave
// traffic. Keys carry compacted POSITION (ascending in original index, so
// tie -> lowest position == lowest original index). Winner coords come from
// a position-indexed LDS table; original index is stored in the table.
__device__ void chain_tail(int t0,
    const float4* __restrict__ cmp,
    float& cxr, float& cyr, float& czr,
    unsigned* pk_lds, unsigned* d2_lds,
    float4* s_ta, float4* s_tb, int lane)
{
  constexpr int E = 16, NPT = 8;
  const int base = lane * E;
  v2f sxp[NPT], syp[NPT], szp[NPT], exp_[NPT], eyp[NPT], ezp[NPT];

#pragma unroll
  for (int e = 0; e < E; ++e) {
    int pos = base + e;
    float4 a = cmp[(size_t)pos * 2];
    float4 b = cmp[(size_t)pos * 2 + 1];
    s_ta[pos] = a; s_tb[pos] = b;
    if (e & 1) {
      sxp[e >> 1].y = a.x; syp[e >> 1].y = a.y; szp[e >> 1].y = a.z;
      exp_[e >> 1].y = a.w; eyp[e >> 1].y = b.x; ezp[e >> 1].y = b.y;
    } else {
      sxp[e >> 1].x = a.x; syp[e >> 1].x = a.y; szp[e >> 1].x = a.z;
      exp_[e >> 1].x = a.w; eyp[e >> 1].x = b.x; ezp[e >> 1].x = b.y;
    }
  }

  float cx = cxr, cy = cyr, cz = czr;

  for (int t = t0; t < KE - 1; ++t) {
    v2f cx2 = {cx, cx}, cy2 = {cy, cy}, cz2 = {cz, cz};
    float av0 = INFINITY, av1 = INFINITY, av2 = INFINITY, av3 = INFINITY;
    int   ai0 = 0x7FFFFFFF, ai1 = 0x7FFFFFFF, ai2 = 0x7FFFFFFF, ai3 = 0x7FFFFFFF;
#pragma unroll
    for (int p = 0; p < NPT; ++p) {
      v2f d2s = dist2p(cx2, cy2, cz2, sxp[p], syp[p], szp[p]);
      v2f d2e = dist2p(cx2, cy2, cz2, exp_[p], eyp[p], ezp[p]);
      v2f dm = __builtin_elementwise_min(d2s, d2e);
      int ix = base + 2 * p;        // compacted POSITION
      int iy = base + 2 * p + 1;
      if ((p & 1) == 0) {
        if (dm.x < av0) { av0 = dm.x; ai0 = ix; }
        if (dm.y < av2) { av2 = dm.y; ai2 = iy; }
      } else {
        if (dm.x < av1) { av1 = dm.x; ai1 = ix; }
        if (dm.y < av3) { av3 = dm.y; ai3 = iy; }
      }
    }
    float mv = av0; int mi = ai0;
    if (av1 < mv || (av1 == mv && ai1 < mi)) { mv = av1; mi = ai1; }
    if (av2 < mv || (av2 == mv && ai2 < mi)) { mv = av2; mi = ai2; }
    if (av3 < mv || (av3 == mv && ai3 < mi)) { mv = av3; mi = ai3; }

    unsigned mvb = __float_as_uint(mv);
    unsigned x = mvb;
    DPPMIN(x, 0x111, 0xf);
    DPPMIN(x, 0x112, 0xf);
    DPPMIN(x, 0x114, 0xf);
    DPPMIN(x, 0x118, 0xf);
    DPPMIN(x, 0x142, 0xa);
    DPPMIN(x, 0x143, 0xc);
    unsigned wmin = (unsigned)__builtin_amdgcn_readlane((int)x, 63);

    u64 ball = __ballot(mvb == wmin);
    int win_lane = __ffsll(ball) - 1;              // uniform (SGPR)
    int wpos = __builtin_amdgcn_readlane(mi, win_lane);  // uniform position

    float4 a = s_ta[wpos];                         // broadcast LDS reads
    float4 b = s_tb[wpos];
    int orig = __float_as_int(b.z);

    // flip: numpy-exact (exact dist2 + exact sqrt compare)
    float da2 = dist2(cx, cy, cz, a.x, a.y, a.z);
    float db2 = dist2(cx, cy, cz, a.w, b.x, b.y);
    int fl = (sqrtf(da2) > sqrtf(db2)) ? 1 : 0;
    cx = fl ? a.x : a.w;
    cy = fl ? a.y : b.x;
    cz = fl ? a.z : b.y;

    if (lane == win_lane) {                        // owner lane (wpos>>4==lane)
      int e = wpos & (E - 1);
#pragma unroll
      for (int k = 0; k < NPT; ++k) {
        if ((e >> 1) == k) {
          if (e & 1) { sxp[k].y = INFINITY; exp_[k].y = INFINITY; }
          else       { sxp[k].x = INFINITY; exp_[k].x = INFINITY; }
        }
      }
      pk_lds[t + 1] = ((unsigned)orig << 1) | (unsigned)fl;
      d2_lds[t]     = wmin;
    }
  }

  cxr = cx; cyr = cy; czr = cz;
}

extern "C" __global__ void __launch_bounds__(NT, 1)
chain_kernel(const float* __restrict__ edges, float* __restrict__ tail,
             int* __restrict__ ws_order, int* __restrict__ ws_flip,
             float* __restrict__ tbl, float4* __restrict__ cmp)
{
  const int tid = threadIdx.x;
  const int lane = tid & 63;
  const int wid = tid >> 6;          // 0..7
  const int base = tid * EPT;

  __shared__ __align__(16) u64 kbuf[2][NW];
  __shared__ float  s_v[NW];
  __shared__ int    s_i[NW];
  __shared__ float  s_m1[NW], s_m2[NW];
  __shared__ unsigned pk_lds[KE];
  __shared__ unsigned d2_lds[KE];
  __shared__ __align__(16) float4 s_ta[1024];   // tail coord table
  __shared__ __align__(16) float4 s_tb[1024];

  // ---- init: load endpoints ----
  v2f sxp[EPT / 2], syp[EPT / 2], szp[EPT / 2];
  v2f exp_[EPT / 2], eyp[EPT / 2], ezp[EPT / 2];
#pragma unroll
  for (int e = 0; e < EPT; ++e) {
    const float* p = edges + (size_t)(base + e) * NPF;
    float a0 = p[0], a1 = p[1], a2 = p[2];
    float b0 = p[NPF - 3], b1 = p[NPF - 2], b2 = p[NPF - 1];
    if (e & 1) {
      sxp[e >> 1].y = a0; syp[e >> 1].y = a1; szp[e >> 1].y = a2;
      exp_[e >> 1].y = b0; eyp[e >> 1].y = b1; ezp[e >> 1].y = b2;
    } else {
      sxp[e >> 1].x = a0; syp[e >> 1].x = a1; szp[e >> 1].x = a2;
      exp_[e >> 1].x = b0; eyp[e >> 1].x = b1; ezp[e >> 1].x = b2;
    }
  }

  // ---- write compact endpoint table (32B/edge, L2-resident) ----
  if (tbl) {
#pragma unroll
    for (int e = 0; e < EPT; ++e) {
      float4 a, b;
      a.x = GETP(sxp, e); a.y = GETP(syp, e); a.z = GETP(szp, e); a.w = GETP(exp_, e);
      b.x = GETP(eyp, e); b.y = GETP(ezp, e); b.z = 0.f; b.w = 0.f;
      ((float4*)tbl)[(size_t)(base + e) * 2]     = a;
      ((float4*)tbl)[(size_t)(base + e) * 2 + 1] = b;
    }
  }

  // ---- lengths; top-10; start_index = max index among them ----
  float len[EPT];
#pragma unroll
  for (int e = 0; e < EPT; ++e)
    len[e] = dist3(GETP(exp_, e), GETP(eyp, e), GETP(ezp, e),
                   GETP(sxp, e), GETP(syp, e), GETP(szp, e));

  unsigned tk = 0;
  int start_index = -1;
  for (int r = 0; r < TOPK_N; ++r) {
    float bv = -INFINITY; int bi = 0x7fffffff;
#pragma unroll
    for (int e = 0; e < EPT; ++e) {
      if ((tk >> e) & 1) continue;
      if (len[e] > bv) { bv = len[e]; bi = base + e; }
    }
    for (int m = 1; m < 64; m <<= 1) {
      float v2 = __shfl_xor(bv, m); int i2 = __shfl_xor(bi, m);
      if (v2 > bv || (v2 == bv && i2 < bi)) { bv = v2; bi = i2; }
    }
    if (lane == 0) { s_v[wid] = bv; s_i[wid] = bi; }
    __syncthreads();
    {
      float cv = s_v[lane & (NW - 1)]; int ci = s_i[lane & (NW - 1)];
      for (int m = 1; m < NW; m <<= 1) {
        float v2 = __shfl_xor(cv, m); int i2 = __shfl_xor(ci, m);
        if (v2 > cv || (v2 == cv && i2 < ci)) { cv = v2; ci = i2; }
      }
      int sel = ci;
      if ((sel / EPT) == tid) tk |= 1u << (sel & (EPT - 1));
      if (sel > start_index) start_index = sel;
    }
    __syncthreads();
  }

  // ---- s0 / e0: uniform global load ----
  float s0x, s0y, s0z, e0x, e0y, e0z;
  {
    const float* p = edges + (size_t)start_index * NPF;
    s0x = p[0];       s0y = p[1];       s0z = p[2];
    e0x = p[NPF - 3]; e0y = p[NPF - 2]; e0z = p[NPF - 1];
  }

  // ---- use_flip0 (numpy-exact; sqrt(min)==min(sqrt)) ----
  {
    float m1 = INFINITY, m2 = INFINITY;
#pragma unroll
    for (int e = 0; e < EPT; ++e) {
      int k = base + e;
      float a = dist2(s0x, s0y, s0z, GETP(sxp, e), GETP(syp, e), GETP(szp, e));
      float b = dist2(s0x, s0y, s0z, GETP(exp_, e), GETP(eyp, e), GETP(ezp, e));
      float c = dist2(e0x, e0y, e0z, GETP(sxp, e), GETP(syp, e), GETP(szp, e));
      float d = dist2(e0x, e0y, e0z, GETP(exp_, e), GETP(eyp, e), GETP(ezp, e));
      float v1 = fminf(a, b), v2 = fminf(c, d);
      if (k == start_index) { v1 = INFINITY; v2 = INFINITY; }
      m1 = fminf(m1, v1);
      m2 = fminf(m2, v2);
    }
    for (int m = 1; m < 64; m <<= 1) {
      m1 = fminf(m1, __shfl_xor(m1, m));
      m2 = fminf(m2, __shfl_xor(m2, m));
    }
    if (lane == 0) { s_m1[wid] = m1; s_m2[wid] = m2; }
  }
  __syncthreads();

  float cx, cy, cz, fx, fy, fz;
  {
    float m1 = s_m1[lane & (NW - 1)], m2 = s_m2[lane & (NW - 1)];
    for (int m = 1; m < NW; m <<= 1) {
      m1 = fminf(m1, __shfl_xor(m1, m));
      m2 = fminf(m2, __shfl_xor(m2, m));
    }
    int flip0 = (sqrtf(m1) < sqrtf(m2)) ? 1 : 0;
    cx = flip0 ? s0x : e0x;  cy = flip0 ? s0y : e0y;  cz = flip0 ? s0z : e0z;
    fx = flip0 ? e0x : s0x;  fy = flip0 ? e0y : s0y;  fz = flip0 ? e0z : s0z;
    if (tid == 0)
      pk_lds[0] = ((unsigned)start_index << 1) | (unsigned)flip0;
  }
  __syncthreads();

  // ---- phased greedy chain ----
  if (cmp) {
    chain_phase<16, true >(0,    4095, edges, (const float4*)tbl, cmp,
                           start_index, cx, cy, cz, pk_lds, d2_lds, kbuf, s_i, tid);
    chain_phase<8, false>(4095, 6143, edges, (const float4*)tbl, cmp,
                           start_index, cx, cy, cz, pk_lds, d2_lds, kbuf, s_i, tid);
    chain_phase<4, false>(6143, 7167, edges, (const float4*)tbl, cmp,
                           start_index, cx, cy, cz, pk_lds, d2_lds, kbuf, s_i, tid);
    if (wid == 0)
      chain_tail(7167, cmp, cx, cy, cz, pk_lds, d2_lds, s_ta, s_tb, lane);
  } else {
    chain_phase<16, true >(0, KE - 1, edges, (const float4*)tbl, cmp,
                           start_index, cx, cy, cz, pk_lds, d2_lds, kbuf, s_i, tid);
  }

  // closing squared distance -> d2_lds[KE-1] (sqrt at flush)
  if (tid == 0)
    d2_lds[KE - 1] = __float_as_uint(dist2(cx, cy, cz, fx, fy, fz));
  __syncthreads();

  // ---- final flush: LDS -> global (order | flips | distances | ws) ----
  float* ord_f = tail;
  float* flp_f = tail + KE;
  float* dst_f = tail + 2 * KE;
#pragma unroll
  for (int k = 0; k < EPT; ++k) {
    int i = tid + k * NT;
    unsigned p = pk_lds[i];
    int w = (int)(p >> 1);
    int f = (int)(p & 1u);
    ord_f[i] = (float)w;
    flp_f[i] = (float)f;
    dst_f[i] = sqrtf(__uint_as_float(d2_lds[i]));
    ws_order[i] = w;
    ws_flip[i]  = f;
  }
}

extern "C" __global__ void __launch_bounds__(256)
gather_kernel(const float* __restrict__ edges, const int* __restrict__ ws_order,
              const int* __restrict__ ws_flip, float* __restrict__ out)
{
  int idx = blockIdx.x * 256 + threadIdx.x;   // < 25165824, fits int
  int i = idx / NPF;
  int f = idx - i * NPF;
  int o  = ws_order[i];
  int fl = ws_flip[i];
  int r = f / 3;
  int c = f - r * 3;
  int srcf = fl ? ((1023 - r) * 3 + c) : f;
  out[idx] = edges[o * NPF + srcf];
}

extern "C" void kernel_launch(void* const* d_in, const int* in_sizes, int n_in,
                              void* d_out, int out_size, void* d_ws, size_t ws_size,
                              hipStream_t stream) {
  (void)in_sizes; (void)n_in; (void)out_size;
  const float* edges = (const float*)d_in[0];
  float* out  = (float*)d_out;
  float* tail = out + (size_t)KE * NPF;        // order | flips | distances
  int* ws_order = (int*)d_ws;
  int* ws_flip  = ws_order + KE;
  size_t need_tbl = (size_t)2 * KE * sizeof(int) + (size_t)KE * 8 * sizeof(float);
  size_t need_cmp = need_tbl + (size_t)4096 * 8 * sizeof(float);
  float* tbl = (ws_size >= need_tbl)
                 ? (float*)((char*)d_ws + (size_t)2 * KE * sizeof(int)) : nullptr;
  float4* cmp = (ws_size >= need_cmp && tbl)
                 ? (float4*)((char*)d_ws + need_tbl) : nullptr;

  hipLaunchKernelGGL(chain_kernel, dim3(1), dim3(NT), 0, stream,
                     edges, tail, ws_order, ws_flip, tbl, cmp);
  hipLaunchKernelGGL(gather_kernel, dim3((KE * NPF) / 256), dim3(256), 0, stream,
                     edges, ws_order, ws_flip, out);
}